// Round 1
// baseline (534.983 us; speedup 1.0000x reference)
//
#include <hip/hip_runtime.h>
#include <math.h>

#define L_SEQ 4096
#define NB 2
#define CDIM 256
#define DIN 512
#define NCHUNK 64
#define CHUNK 64

__device__ __forceinline__ float siluf(float x){ return x / (1.f + __expf(-x)); }
__device__ __forceinline__ float geluf(float x){ return 0.5f*x*(1.f+erff(x*0.70710678118654752f)); }
__device__ __forceinline__ float softplusf(float x){ return fmaxf(x,0.f) + log1pf(__expf(-fabsf(x))); }

// ---------------- LayerNorm + NCHW->(B,L,C) transpose ----------------
__global__ __launch_bounds__(256)
void ln_kernel(const float* __restrict__ x, const float* __restrict__ g,
               const float* __restrict__ bta, float* __restrict__ y){
  int bl = blockIdx.x;            // b*4096 + l
  int b = bl >> 12; int l = bl & 4095;
  int c = threadIdx.x;
  float v = x[((size_t)(b*CDIM + c))*L_SEQ + l];
  float s = v, s2 = v*v;
  #pragma unroll
  for (int off=32; off>0; off>>=1){ s += __shfl_down(s,off); s2 += __shfl_down(s2,off); }
  __shared__ float ps[4], ps2[4];
  int wid = threadIdx.x >> 6;
  if ((threadIdx.x & 63)==0){ ps[wid]=s; ps2[wid]=s2; }
  __syncthreads();
  s  = ps[0]+ps[1]+ps[2]+ps[3];
  s2 = ps2[0]+ps2[1]+ps2[2]+ps2[3];
  float mean = s * (1.f/256.f);
  float var  = s2*(1.f/256.f) - mean*mean;
  float rstd = rsqrtf(var + 1e-5f);
  y[(size_t)bl*CDIM + c] = (v-mean)*rstd*g[c] + bta[c];
}

// ---------------- Generic tiled fp32 GEMM: out[m,n] = act(sum_k A[m,k]*W[n,k] + bias) + res ----------------
// ACT: 0 none, 1 gelu, 2 softplus.  TOUT: write (B,C,H,W) transposed output (N must be 256).
template<int ACT, bool BIAS, bool RES, bool TOUT>
__global__ __launch_bounds__(256)
void gemm_kernel(const float* __restrict__ A, int lda,
                 const float* __restrict__ W, int ldw,
                 const float* __restrict__ bias,
                 const float* __restrict__ res,
                 float* __restrict__ out,
                 int M, int N, int K){
  __shared__ float As[16][68];
  __shared__ float Bs[16][68];
  int tid = threadIdx.x;
  int m0 = blockIdx.x*64, n0 = blockIdx.y*64;
  int row = tid >> 2, quad = tid & 3;
  int ty = tid >> 4, tx = tid & 15;
  float acc[4][4] = {};
  for (int k0 = 0; k0 < K; k0 += 16){
    float4 av = make_float4(0,0,0,0);
    if (m0+row < M)
      av = *(const float4*)(A + (size_t)(m0+row)*lda + k0 + quad*4);
    float4 bv = make_float4(0,0,0,0);
    if (n0+row < N)
      bv = *(const float4*)(W + (size_t)(n0+row)*ldw + k0 + quad*4);
    As[quad*4+0][row]=av.x; As[quad*4+1][row]=av.y; As[quad*4+2][row]=av.z; As[quad*4+3][row]=av.w;
    Bs[quad*4+0][row]=bv.x; Bs[quad*4+1][row]=bv.y; Bs[quad*4+2][row]=bv.z; Bs[quad*4+3][row]=bv.w;
    __syncthreads();
    #pragma unroll
    for (int kk=0; kk<16; kk++){
      float4 a = *(const float4*)&As[kk][ty*4];
      float4 b = *(const float4*)&Bs[kk][tx*4];
      acc[0][0] += a.x*b.x; acc[0][1] += a.x*b.y; acc[0][2] += a.x*b.z; acc[0][3] += a.x*b.w;
      acc[1][0] += a.y*b.x; acc[1][1] += a.y*b.y; acc[1][2] += a.y*b.z; acc[1][3] += a.y*b.w;
      acc[2][0] += a.z*b.x; acc[2][1] += a.z*b.y; acc[2][2] += a.z*b.z; acc[2][3] += a.z*b.w;
      acc[3][0] += a.w*b.x; acc[3][1] += a.w*b.y; acc[3][2] += a.w*b.z; acc[3][3] += a.w*b.w;
    }
    __syncthreads();
  }
  #pragma unroll
  for (int i=0;i<4;i++){
    int m = m0 + ty*4 + i;
    if (m >= M) continue;
    #pragma unroll
    for (int j=0;j<4;j++){
      int n = n0 + tx*4 + j;
      if (n >= N) continue;
      float v = acc[i][j];
      if (BIAS) v += bias[n];
      if (ACT==1) v = geluf(v);
      else if (ACT==2) v = softplusf(v);
      if (RES) v += res[(size_t)m*N + n];
      if (TOUT){
        int b = m >> 12, l = m & 4095;
        out[((size_t)(b*N + n))*L_SEQ + l] = v;
      } else {
        out[(size_t)m*N + n] = v;
      }
    }
  }
}

// ---------------- Depthwise causal conv (k=4) + SiLU ----------------
__global__ __launch_bounds__(256)
void conv_silu_kernel(const float* __restrict__ xz, const float* __restrict__ w,
                      const float* __restrict__ cb, float* __restrict__ xc){
  int i = blockIdx.x*256 + threadIdx.x;   // NB*L*DIN = 4194304
  int d = i & 511;
  int l = (i >> 9) & 4095;
  int b = i >> 21;
  float acc = cb[d];
  float w0=w[d*4+0], w1=w[d*4+1], w2=w[d*4+2], w3=w[d*4+3];
  const float* base = xz + (size_t)(b*L_SEQ)*1024 + d;
  if (l>=3) acc += w0*base[(size_t)(l-3)*1024];
  if (l>=2) acc += w1*base[(size_t)(l-2)*1024];
  if (l>=1) acc += w2*base[(size_t)(l-1)*1024];
  acc += w3*base[(size_t)l*1024];
  xc[i] = siluf(acc);
}

// ---------------- Scan phase A: per-chunk local state + sum(delta) ----------------
__global__ __launch_bounds__(256)
void scanA_kernel(const float* __restrict__ delta, const float* __restrict__ xc,
                  const float* __restrict__ xdbl, const float* __restrict__ A_log,
                  float* __restrict__ S, float* __restrict__ sumd){
  __shared__ float del_s[CHUNK][16];
  __shared__ float x_s[CHUNK][16];
  __shared__ float B_s[CHUNK][16];
  int bx = blockIdx.x;
  int dg = bx & 31; int c = (bx>>5) & 63; int b = bx >> 11;
  int tid = threadIdx.x;
  for (int i = tid; i < CHUNK*16; i += 256){
    int t = i >> 4, j = i & 15;
    int l = c*CHUNK + t;
    size_t rb = (size_t)(b*L_SEQ + l);
    del_s[t][j] = delta[rb*512 + dg*16 + j];
    x_s[t][j]   = xc[rb*512 + dg*16 + j];
    B_s[t][j]   = xdbl[rb*48 + 16 + j];
  }
  __syncthreads();
  int dd = tid >> 4, s = tid & 15;
  int d = dg*16 + dd;
  float Ads = -__expf(A_log[d*16 + s]);
  float h = 0.f, sd = 0.f;
  #pragma unroll 4
  for (int t=0; t<CHUNK; t++){
    float dlt = del_s[t][dd];
    h = __expf(dlt*Ads)*h + dlt * x_s[t][dd] * B_s[t][s];
    sd += dlt;
  }
  size_t ci = (size_t)(b*NCHUNK + c)*512 + d;
  S[ci*16 + s] = h;
  if (s==0) sumd[ci] = sd;
}

// ---------------- Scan phase B: sequential combine across chunks ----------------
__global__ __launch_bounds__(256)
void scanB_kernel(const float* __restrict__ S, const float* __restrict__ sumd,
                  const float* __restrict__ A_log, float* __restrict__ Hinit){
  int g = blockIdx.x*256 + threadIdx.x;  // 16384 = 2*512*16
  int s = g & 15, d = (g>>4) & 511, b = g >> 13;
  float Ads = -__expf(A_log[d*16+s]);
  float H = 0.f;
  for (int c=0;c<NCHUNK;c++){
    size_t ci = (size_t)(b*NCHUNK+c)*512 + d;
    Hinit[ci*16+s] = H;
    H = __expf(Ads*sumd[ci])*H + S[ci*16+s];
  }
}

// ---------------- Scan phase C: seeded re-scan, y = sum_s h*C, +D*x, *silu(z) ----------------
__global__ __launch_bounds__(256)
void scanC_kernel(const float* __restrict__ delta, const float* __restrict__ xc,
                  const float* __restrict__ xdbl, const float* __restrict__ xz,
                  const float* __restrict__ A_log, const float* __restrict__ Dp,
                  const float* __restrict__ Hinit, float* __restrict__ ys){
  __shared__ float del_s[CHUNK][16];
  __shared__ float x_s[CHUNK][16];
  __shared__ float B_s[CHUNK][16];
  __shared__ float C_s[CHUNK][16];
  __shared__ float ys_s[CHUNK][16];
  int bx = blockIdx.x;
  int dg = bx & 31; int c = (bx>>5) & 63; int b = bx >> 11;
  int tid = threadIdx.x;
  for (int i = tid; i < CHUNK*16; i += 256){
    int t = i >> 4, j = i & 15;
    int l = c*CHUNK + t;
    size_t rb = (size_t)(b*L_SEQ + l);
    del_s[t][j] = delta[rb*512 + dg*16 + j];
    x_s[t][j]   = xc[rb*512 + dg*16 + j];
    B_s[t][j]   = xdbl[rb*48 + 16 + j];
    C_s[t][j]   = xdbl[rb*48 + 32 + j];
  }
  __syncthreads();
  int dd = tid >> 4, s = tid & 15;
  int d = dg*16 + dd;
  float Ads = -__expf(A_log[d*16 + s]);
  size_t ci = (size_t)(b*NCHUNK + c)*512 + d;
  float h = Hinit[ci*16 + s];
  float Dv = Dp[d];
  #pragma unroll 4
  for (int t=0; t<CHUNK; t++){
    float dlt = del_s[t][dd];
    h = __expf(dlt*Ads)*h + dlt * x_s[t][dd] * B_s[t][s];
    float p = h * C_s[t][s];
    p += __shfl_xor(p,1); p += __shfl_xor(p,2); p += __shfl_xor(p,4); p += __shfl_xor(p,8);
    if (s==0) ys_s[t][dd] = p + Dv*x_s[t][dd];
  }
  __syncthreads();
  for (int i = tid; i < CHUNK*16; i += 256){
    int t = i >> 4, j = i & 15;
    int l = c*CHUNK + t;
    size_t rb = (size_t)(b*L_SEQ + l);
    float zv = xz[rb*1024 + 512 + dg*16 + j];
    ys[rb*512 + dg*16 + j] = ys_s[t][j] * siluf(zv);
  }
}

extern "C" void kernel_launch(void* const* d_in, const int* in_sizes, int n_in,
                              void* d_out, int out_size, void* d_ws, size_t ws_size,
                              hipStream_t stream){
  const float* x         = (const float*)d_in[0];
  const float* norm_g    = (const float*)d_in[1];
  const float* norm_b    = (const float*)d_in[2];
  const float* in_proj_w = (const float*)d_in[3];
  const float* conv_w    = (const float*)d_in[4];
  const float* conv_b    = (const float*)d_in[5];
  const float* x_proj_w  = (const float*)d_in[6];
  const float* dt_proj_w = (const float*)d_in[7];
  const float* dt_proj_b = (const float*)d_in[8];
  const float* A_log     = (const float*)d_in[9];
  const float* Dp        = (const float*)d_in[10];
  const float* out_proj_w= (const float*)d_in[11];
  const float* w1        = (const float*)d_in[12];
  const float* b1        = (const float*)d_in[13];
  const float* w2        = (const float*)d_in[14];
  const float* b2        = (const float*)d_in[15];

  float* ws    = (float*)d_ws;
  float* yln   = ws;                         // 2,097,152
  float* xz    = yln  + (size_t)2097152;     // 8,388,608  (z kept; reused as ffn_h after scanC)
  float* xc    = xz   + (size_t)8388608;     // 4,194,304  (reused in-place as ys by scanC)
  float* xdbl  = xc   + (size_t)4194304;     // 393,216
  float* delta = xdbl + (size_t)393216;      // 4,194,304  (reused as ymid after scanC)
  float* S     = delta+ (size_t)4194304;     // 1,048,576
  float* sumd  = S    + (size_t)1048576;     // 65,536
  float* hinit = sumd + (size_t)65536;       // 1,048,576
  float* ys    = xc;       // alias: scanC reads xc (staged) before writing ys at identical offsets
  float* ymid  = delta;    // alias: delta dead after scanC
  float* ffnh  = xz;       // alias: z dead after scanC

  // 1. LayerNorm (+ transpose to (B,L,C))
  ln_kernel<<<NB*L_SEQ, 256, 0, stream>>>(x, norm_g, norm_b, yln);
  // 2. in_proj: (8192,256)x(1024,256)^T -> xz (8192,1024)
  gemm_kernel<0,false,false,false><<<dim3(128,16), 256, 0, stream>>>(yln,256, in_proj_w,256, nullptr,nullptr, xz, 8192,1024,256);
  // 3. depthwise causal conv + silu -> xc (8192,512)
  conv_silu_kernel<<<16384, 256, 0, stream>>>(xz, conv_w, conv_b, xc);
  // 4. x_proj: (8192,512)x(48,512)^T -> xdbl (8192,48)
  gemm_kernel<0,false,false,false><<<dim3(128,1), 256, 0, stream>>>(xc,512, x_proj_w,512, nullptr,nullptr, xdbl, 8192,48,512);
  // 5. dt_proj + softplus: (8192,16[of 48])x(512,16)^T -> delta (8192,512)
  gemm_kernel<2,true,false,false><<<dim3(128,8), 256, 0, stream>>>(xdbl,48, dt_proj_w,16, dt_proj_b,nullptr, delta, 8192,512,16);
  // 6-8. chunked selective scan
  scanA_kernel<<<NB*NCHUNK*32, 256, 0, stream>>>(delta, xc, xdbl, A_log, S, sumd);
  scanB_kernel<<<64, 256, 0, stream>>>(S, sumd, A_log, hinit);
  scanC_kernel<<<NB*NCHUNK*32, 256, 0, stream>>>(delta, xc, xdbl, xz, A_log, Dp, hinit, ys);
  // 9. out_proj + residual(yln): (8192,512)x(256,512)^T -> ymid (8192,256)
  gemm_kernel<0,false,true,false><<<dim3(128,4), 256, 0, stream>>>(ys,512, out_proj_w,512, nullptr, yln, ymid, 8192,256,512);
  // 10. ffn1 + gelu: (8192,256)x(1024,256)^T -> ffnh (8192,1024)
  gemm_kernel<1,true,false,false><<<dim3(128,16), 256, 0, stream>>>(ymid,256, w1,256, b1, nullptr, ffnh, 8192,1024,256);
  // 11. ffn2 + bias + residual(ymid), write transposed to (B,C,H,W)
  gemm_kernel<0,true,true,true><<<dim3(128,4), 256, 0, stream>>>(ffnh,1024, w2,1024, b2, ymid, (float*)d_out, 8192,256,1024);
}

// Round 2
// 336.734 us; speedup vs baseline: 1.5887x; 1.5887x over previous
//
#include <hip/hip_runtime.h>
#include <math.h>

#define L_SEQ 4096
#define NB 2
#define CDIM 256
#define DIN 512
#define NCHUNK 64
#define CHUNK 64

typedef __bf16 bf16x8 __attribute__((ext_vector_type(8)));
typedef float f32x4 __attribute__((ext_vector_type(4)));

__device__ __forceinline__ float siluf(float x){ return x / (1.f + __expf(-x)); }
__device__ __forceinline__ float geluf(float x){ return 0.5f*x*(1.f+erff(x*0.70710678118654752f)); }
__device__ __forceinline__ float softplusf(float x){ return fmaxf(x,0.f) + log1pf(__expf(-fabsf(x))); }

__device__ __forceinline__ void gl_lds16(const __bf16* g, const __bf16* lds_base){
  __builtin_amdgcn_global_load_lds(
      (const __attribute__((address_space(1))) unsigned int*)g,
      (__attribute__((address_space(3))) unsigned int*)lds_base, 16, 0, 0);
}

// ---------------- cast 4 weight matrices to bf16 ----------------
__global__ __launch_bounds__(256)
void cast_w_kernel(const float* __restrict__ inw, const float* __restrict__ outw,
                   const float* __restrict__ w1, const float* __restrict__ w2,
                   __bf16* __restrict__ dst){
  int i = blockIdx.x*256 + threadIdx.x;   // total 917504
  float v;
  if (i < 262144) v = inw[i];
  else if (i < 393216) v = outw[i-262144];
  else if (i < 655360) v = w1[i-393216];
  else v = w2[i-655360];
  dst[i] = (__bf16)v;
}

// ---------------- LayerNorm + NCHW->(B,L,C); writes f32 + bf16 ----------------
__global__ __launch_bounds__(256)
void ln_kernel(const float* __restrict__ x, const float* __restrict__ g,
               const float* __restrict__ bta, float* __restrict__ y,
               __bf16* __restrict__ ybf){
  int bl = blockIdx.x;            // b*4096 + l
  int b = bl >> 12; int l = bl & 4095;
  int c = threadIdx.x;
  float v = x[((size_t)(b*CDIM + c))*L_SEQ + l];
  float s = v, s2 = v*v;
  #pragma unroll
  for (int off=32; off>0; off>>=1){ s += __shfl_down(s,off); s2 += __shfl_down(s2,off); }
  __shared__ float ps[4], ps2[4];
  int wid = threadIdx.x >> 6;
  if ((threadIdx.x & 63)==0){ ps[wid]=s; ps2[wid]=s2; }
  __syncthreads();
  s  = ps[0]+ps[1]+ps[2]+ps[3];
  s2 = ps2[0]+ps2[1]+ps2[2]+ps2[3];
  float mean = s * (1.f/256.f);
  float var  = s2*(1.f/256.f) - mean*mean;
  float rstd = rsqrtf(var + 1e-5f);
  float o = (v-mean)*rstd*g[c] + bta[c];
  y[(size_t)bl*CDIM + c] = o;
  ybf[(size_t)bl*CDIM + c] = (__bf16)o;
}

// ---------------- bf16 MFMA GEMM: out[m,n] = act(sum_k A[m,k]*W[n,k] + bias) + res ----------------
// BM: 128 (waves 2x2 of 64x64) or 64 (waves 1x4 of 64x32). BN fixed 128. BK=32.
template<int BM, int ACT, bool BIAS, bool RES, bool TOUT, bool OF32, bool OBF>
__global__ __launch_bounds__(256)
void mgemm_kernel(const __bf16* __restrict__ A, const __bf16* __restrict__ W,
                  const int K, const int N,
                  const float* __restrict__ bias, const float* __restrict__ res,
                  float* __restrict__ out32, __bf16* __restrict__ outbf){
  constexpr int NWN = (BM==128) ? 2 : 4;   // waves along N
  constexpr int NT  = 8 / NWN;             // 16-col tiles per wave (4 or 2)
  __shared__ __bf16 Asm[BM*32];
  __shared__ __bf16 Bsm[128*32];
  const int tid = threadIdx.x;
  const int wid = tid >> 6, lane = tid & 63;
  const int lq = lane >> 4, lr = lane & 15;
  const int wmbase = (BM==128) ? (wid>>1)*64 : 0;
  const int wnbase = (BM==128) ? (wid&1)*64 : wid*32;
  const size_t m0 = (size_t)blockIdx.x * BM;
  const size_t n0 = (size_t)blockIdx.y * 128;

  // staging: chunkid=q*256+tid; row=chunkid>>2; store global chunk (c ^ ((row>>1)&3)) at linear slot c
  const int rowS = tid >> 2;
  const int cg   = (tid & 3) ^ ((rowS >> 1) & 3);
  const __bf16* Ag = A + m0*K + (size_t)rowS*K + cg*8;
  const __bf16* Wg = W + n0*K + (size_t)rowS*K + cg*8;

  // reader LDS byte offsets (swizzled): element chunk q of row r lives at slot q^((r>>1)&3)
  int a_off[4], b_off[NT];
  #pragma unroll
  for (int mt=0; mt<4; mt++){
    int r = wmbase + mt*16 + lr;
    a_off[mt] = r*64 + ((lq ^ ((r>>1)&3))<<4);
  }
  #pragma unroll
  for (int nt=0; nt<NT; nt++){
    int r = wnbase + nt*16 + lr;
    b_off[nt] = r*64 + ((lq ^ ((r>>1)&3))<<4);
  }

  f32x4 acc[4][NT] = {};

  for (int k0 = 0; k0 < K; k0 += 32){
    gl_lds16(Ag + k0, &Asm[wid*512]);
    if constexpr (BM==128) gl_lds16(Ag + (size_t)64*K + k0, &Asm[2048 + wid*512]);
    gl_lds16(Wg + k0, &Bsm[wid*512]);
    gl_lds16(Wg + (size_t)64*K + k0, &Bsm[2048 + wid*512]);
    __syncthreads();

    bf16x8 av[4], bv[NT];
    #pragma unroll
    for (int mt=0; mt<4; mt++) av[mt] = *(const bf16x8*)((const char*)Asm + a_off[mt]);
    #pragma unroll
    for (int nt=0; nt<NT; nt++) bv[nt] = *(const bf16x8*)((const char*)Bsm + b_off[nt]);
    #pragma unroll
    for (int mt=0; mt<4; mt++)
      #pragma unroll
      for (int nt=0; nt<NT; nt++)
        acc[mt][nt] = __builtin_amdgcn_mfma_f32_16x16x32_bf16(av[mt], bv[nt], acc[mt][nt], 0, 0, 0);
    __syncthreads();
  }

  // epilogue: C/D layout col=lane&15, row=(lane>>4)*4+reg  [m89/m91]
  #pragma unroll
  for (int mt=0; mt<4; mt++){
    #pragma unroll
    for (int r=0; r<4; r++){
      size_t m = m0 + wmbase + mt*16 + lq*4 + r;
      #pragma unroll
      for (int nt=0; nt<NT; nt++){
        size_t n = n0 + wnbase + nt*16 + lr;
        float v = acc[mt][nt][r];
        if (BIAS) v += bias[n];
        if (ACT==1) v = geluf(v);
        if (RES) v += res[m*(size_t)N + n];
        if (TOUT){
          size_t b = m >> 12, l = m & 4095;
          out32[((b*(size_t)N + n)<<12) + l] = v;
        } else {
          if (OF32) out32[m*(size_t)N + n] = v;
          if (OBF)  outbf[m*(size_t)N + n] = (__bf16)v;
        }
      }
    }
  }
}

// ---------------- fp32 tiled GEMM (small shapes: x_proj N=48, dt_proj K=16) ----------------
template<int ACT, bool BIAS>
__global__ __launch_bounds__(256)
void gemm_kernel(const float* __restrict__ A, int lda,
                 const float* __restrict__ W, int ldw,
                 const float* __restrict__ bias,
                 float* __restrict__ out,
                 int M, int N, int K){
  __shared__ float As[16][68];
  __shared__ float Bs[16][68];
  int tid = threadIdx.x;
  int m0 = blockIdx.x*64, n0 = blockIdx.y*64;
  int row = tid >> 2, quad = tid & 3;
  int ty = tid >> 4, tx = tid & 15;
  float acc[4][4] = {};
  for (int k0 = 0; k0 < K; k0 += 16){
    float4 av = make_float4(0,0,0,0);
    if (m0+row < M)
      av = *(const float4*)(A + (size_t)(m0+row)*lda + k0 + quad*4);
    float4 bv = make_float4(0,0,0,0);
    if (n0+row < N)
      bv = *(const float4*)(W + (size_t)(n0+row)*ldw + k0 + quad*4);
    As[quad*4+0][row]=av.x; As[quad*4+1][row]=av.y; As[quad*4+2][row]=av.z; As[quad*4+3][row]=av.w;
    Bs[quad*4+0][row]=bv.x; Bs[quad*4+1][row]=bv.y; Bs[quad*4+2][row]=bv.z; Bs[quad*4+3][row]=bv.w;
    __syncthreads();
    #pragma unroll
    for (int kk=0; kk<16; kk++){
      float4 a = *(const float4*)&As[kk][ty*4];
      float4 b = *(const float4*)&Bs[kk][tx*4];
      acc[0][0] += a.x*b.x; acc[0][1] += a.x*b.y; acc[0][2] += a.x*b.z; acc[0][3] += a.x*b.w;
      acc[1][0] += a.y*b.x; acc[1][1] += a.y*b.y; acc[1][2] += a.y*b.z; acc[1][3] += a.y*b.w;
      acc[2][0] += a.z*b.x; acc[2][1] += a.z*b.y; acc[2][2] += a.z*b.z; acc[2][3] += a.z*b.w;
      acc[3][0] += a.w*b.x; acc[3][1] += a.w*b.y; acc[3][2] += a.w*b.z; acc[3][3] += a.w*b.w;
    }
    __syncthreads();
  }
  #pragma unroll
  for (int i=0;i<4;i++){
    int m = m0 + ty*4 + i;
    if (m >= M) continue;
    #pragma unroll
    for (int j=0;j<4;j++){
      int n = n0 + tx*4 + j;
      if (n >= N) continue;
      float v = acc[i][j];
      if (BIAS) v += bias[n];
      if (ACT==2) v = softplusf(v);
      out[(size_t)m*N + n] = v;
    }
  }
}

// ---------------- Depthwise causal conv (k=4) + SiLU ----------------
__global__ __launch_bounds__(256)
void conv_silu_kernel(const float* __restrict__ xz, const float* __restrict__ w,
                      const float* __restrict__ cb, float* __restrict__ xc){
  int i = blockIdx.x*256 + threadIdx.x;   // NB*L*DIN = 4194304
  int d = i & 511;
  int l = (i >> 9) & 4095;
  int b = i >> 21;
  float acc = cb[d];
  float w0=w[d*4+0], w1=w[d*4+1], w2=w[d*4+2], w3=w[d*4+3];
  const float* base = xz + (size_t)(b*L_SEQ)*1024 + d;
  if (l>=3) acc += w0*base[(size_t)(l-3)*1024];
  if (l>=2) acc += w1*base[(size_t)(l-2)*1024];
  if (l>=1) acc += w2*base[(size_t)(l-1)*1024];
  acc += w3*base[(size_t)l*1024];
  xc[i] = siluf(acc);
}

// ---------------- Scan phase A: per-chunk local state + sum(delta) ----------------
__global__ __launch_bounds__(256)
void scanA_kernel(const float* __restrict__ delta, const float* __restrict__ xc,
                  const float* __restrict__ xdbl, const float* __restrict__ A_log,
                  float* __restrict__ S, float* __restrict__ sumd){
  __shared__ float del_s[CHUNK][16];
  __shared__ float x_s[CHUNK][16];
  __shared__ float B_s[CHUNK][16];
  int bx = blockIdx.x;
  int dg = bx & 31; int c = (bx>>5) & 63; int b = bx >> 11;
  int tid = threadIdx.x;
  for (int i = tid; i < CHUNK*16; i += 256){
    int t = i >> 4, j = i & 15;
    int l = c*CHUNK + t;
    size_t rb = (size_t)(b*L_SEQ + l);
    del_s[t][j] = delta[rb*512 + dg*16 + j];
    x_s[t][j]   = xc[rb*512 + dg*16 + j];
    B_s[t][j]   = xdbl[rb*48 + 16 + j];
  }
  __syncthreads();
  int dd = tid >> 4, s = tid & 15;
  int d = dg*16 + dd;
  float Ads = -__expf(A_log[d*16 + s]);
  float h = 0.f, sd = 0.f;
  #pragma unroll 4
  for (int t=0; t<CHUNK; t++){
    float dlt = del_s[t][dd];
    h = __expf(dlt*Ads)*h + dlt * x_s[t][dd] * B_s[t][s];
    sd += dlt;
  }
  size_t ci = (size_t)(b*NCHUNK + c)*512 + d;
  S[ci*16 + s] = h;
  if (s==0) sumd[ci] = sd;
}

// ---------------- Scan phase B: sequential combine (in place: S -> Hinit) ----------------
__global__ __launch_bounds__(256)
void scanB_kernel(float* __restrict__ SH, const float* __restrict__ sumd,
                  const float* __restrict__ A_log){
  int g = blockIdx.x*256 + threadIdx.x;  // 16384 = 2*512*16
  int s = g & 15, d = (g>>4) & 511, b = g >> 13;
  float Ads = -__expf(A_log[d*16+s]);
  float H = 0.f;
  for (int c=0;c<NCHUNK;c++){
    size_t ci = (size_t)(b*NCHUNK+c)*512 + d;
    float sv = SH[ci*16+s];
    SH[ci*16+s] = H;
    H = __expf(Ads*sumd[ci])*H + sv;
  }
}

// ---------------- Scan phase C: seeded re-scan, y=sum_s h*C, +D*x, *silu(z) -> bf16 ----------------
__global__ __launch_bounds__(256)
void scanC_kernel(const float* __restrict__ delta, const float* __restrict__ xc,
                  const float* __restrict__ xdbl, const float* __restrict__ xz,
                  const float* __restrict__ A_log, const float* __restrict__ Dp,
                  const float* __restrict__ Hinit, __bf16* __restrict__ ys){
  __shared__ float del_s[CHUNK][16];
  __shared__ float x_s[CHUNK][16];
  __shared__ float B_s[CHUNK][16];
  __shared__ float C_s[CHUNK][16];
  __shared__ float ys_s[CHUNK][16];
  int bx = blockIdx.x;
  int dg = bx & 31; int c = (bx>>5) & 63; int b = bx >> 11;
  int tid = threadIdx.x;
  for (int i = tid; i < CHUNK*16; i += 256){
    int t = i >> 4, j = i & 15;
    int l = c*CHUNK + t;
    size_t rb = (size_t)(b*L_SEQ + l);
    del_s[t][j] = delta[rb*512 + dg*16 + j];
    x_s[t][j]   = xc[rb*512 + dg*16 + j];
    B_s[t][j]   = xdbl[rb*48 + 16 + j];
    C_s[t][j]   = xdbl[rb*48 + 32 + j];
  }
  __syncthreads();
  int dd = tid >> 4, s = tid & 15;
  int d = dg*16 + dd;
  float Ads = -__expf(A_log[d*16 + s]);
  size_t ci = (size_t)(b*NCHUNK + c)*512 + d;
  float h = Hinit[ci*16 + s];
  float Dv = Dp[d];
  #pragma unroll 4
  for (int t=0; t<CHUNK; t++){
    float dlt = del_s[t][dd];
    h = __expf(dlt*Ads)*h + dlt * x_s[t][dd] * B_s[t][s];
    float p = h * C_s[t][s];
    p += __shfl_xor(p,1); p += __shfl_xor(p,2); p += __shfl_xor(p,4); p += __shfl_xor(p,8);
    if (s==0) ys_s[t][dd] = p + Dv*x_s[t][dd];
  }
  __syncthreads();
  for (int i = tid; i < CHUNK*16; i += 256){
    int t = i >> 4, j = i & 15;
    int l = c*CHUNK + t;
    size_t rb = (size_t)(b*L_SEQ + l);
    float zv = xz[rb*1024 + 512 + dg*16 + j];
    ys[rb*512 + dg*16 + j] = (__bf16)(ys_s[t][j] * siluf(zv));
  }
}

extern "C" void kernel_launch(void* const* d_in, const int* in_sizes, int n_in,
                              void* d_out, int out_size, void* d_ws, size_t ws_size,
                              hipStream_t stream){
  const float* x         = (const float*)d_in[0];
  const float* norm_g    = (const float*)d_in[1];
  const float* norm_b    = (const float*)d_in[2];
  const float* in_proj_w = (const float*)d_in[3];
  const float* conv_w    = (const float*)d_in[4];
  const float* conv_b    = (const float*)d_in[5];
  const float* x_proj_w  = (const float*)d_in[6];
  const float* dt_proj_w = (const float*)d_in[7];
  const float* dt_proj_b = (const float*)d_in[8];
  const float* A_log     = (const float*)d_in[9];
  const float* Dp        = (const float*)d_in[10];
  const float* out_proj_w= (const float*)d_in[11];
  const float* w1        = (const float*)d_in[12];
  const float* b1        = (const float*)d_in[13];
  const float* w2        = (const float*)d_in[14];
  const float* b2        = (const float*)d_in[15];

  float* ws   = (float*)d_ws;
  float* yln  = ws;                          // 2,097,152 f32 (live: ln -> out_proj residual)
  float* xz   = yln + 2097152;               // 8,388,608 f32 (in_proj -> scanC; then ffnh_bf)
  float* xc   = xz + 8388608;                // 4,194,304 f32
  float* delta= xc + 4194304;                // 4,194,304 f32 (dt_proj -> scanC; then ymid/ymid_bf)
  float* xdbl = delta + 4194304;             //   393,216 f32
  float* SH   = xdbl + 393216;               // 1,048,576 f32 (S, then Hinit in place)
  float* sumd = SH + 1048576;                //    65,536 f32
  __bf16* wbf = (__bf16*)(sumd + 65536);     //   917,504 bf16 (= 458,752 f32 slots)
  float* dual = (float*)wbf + 458752;        // 2,097,152 f32 slot: ylnbf early, ysbf late
  __bf16* ylnbf = (__bf16*)dual;             // 2,097,152 bf16 (dead after in_proj)
  __bf16* ysbf  = (__bf16*)dual;             // 4,194,304 bf16 (written by scanC)
  float*  ymid   = delta;                    // 2,097,152 f32 (after scanC, delta dead)
  __bf16* ymidbf = (__bf16*)(delta + 2097152);
  __bf16* ffnh   = (__bf16*)xz;              // 8,388,608 bf16 (after scanC, xz dead)
  __bf16* wbf_in = wbf;                      // 1024x256
  __bf16* wbf_out= wbf + 262144;             // 256x512
  __bf16* wbf_w1 = wbf + 393216;             // 1024x256
  __bf16* wbf_w2 = wbf + 655360;             // 256x1024

  // 0. weights -> bf16
  cast_w_kernel<<<3584, 256, 0, stream>>>(in_proj_w, out_proj_w, w1, w2, wbf);
  // 1. LayerNorm (+ transpose), f32 + bf16
  ln_kernel<<<NB*L_SEQ, 256, 0, stream>>>(x, norm_g, norm_b, yln, ylnbf);
  // 2. in_proj (MFMA): (8192,256)x(1024,256)^T -> xz f32
  mgemm_kernel<128,0,false,false,false,true,false><<<dim3(64,8), 256, 0, stream>>>(
      ylnbf, wbf_in, 256, 1024, nullptr, nullptr, xz, nullptr);
  // 3. depthwise causal conv + silu -> xc f32
  conv_silu_kernel<<<16384, 256, 0, stream>>>(xz, conv_w, conv_b, xc);
  // 4. x_proj (fp32): (8192,512)x(48,512)^T -> xdbl
  gemm_kernel<0,false><<<dim3(128,1), 256, 0, stream>>>(xc,512, x_proj_w,512, nullptr, xdbl, 8192,48,512);
  // 5. dt_proj + softplus (fp32): -> delta
  gemm_kernel<2,true><<<dim3(128,8), 256, 0, stream>>>(xdbl,48, dt_proj_w,16, dt_proj_b, delta, 8192,512,16);
  // 6-8. chunked selective scan
  scanA_kernel<<<NB*NCHUNK*32, 256, 0, stream>>>(delta, xc, xdbl, A_log, SH, sumd);
  scanB_kernel<<<64, 256, 0, stream>>>(SH, sumd, A_log);
  scanC_kernel<<<NB*NCHUNK*32, 256, 0, stream>>>(delta, xc, xdbl, xz, A_log, Dp, SH, ysbf);
  // 9. out_proj (MFMA) + residual(yln): -> ymid f32 + bf16
  mgemm_kernel<64,0,false,true,false,true,true><<<dim3(128,2), 256, 0, stream>>>(
      ysbf, wbf_out, 512, 256, nullptr, yln, ymid, ymidbf);
  // 10. ffn1 + gelu (MFMA): -> ffnh bf16
  mgemm_kernel<128,1,true,false,false,false,true><<<dim3(64,8), 256, 0, stream>>>(
      ymidbf, wbf_w1, 256, 1024, b1, nullptr, nullptr, ffnh);
  // 11. ffn2 + bias + residual(ymid) (MFMA), transposed write to (B,C,H,W)
  mgemm_kernel<64,0,true,true,true,true,false><<<dim3(128,2), 256, 0, stream>>>(
      ffnh, wbf_w2, 1024, 256, b2, ymid, (float*)d_out, nullptr);
}

// Round 3
// 268.964 us; speedup vs baseline: 1.9891x; 1.2520x over previous
//
#include <hip/hip_runtime.h>
#include <math.h>

#define L_SEQ 4096
#define NB 2
#define CDIM 256
#define DIN 512
#define NCHUNK 128
#define CHUNK 32

typedef __bf16 bf16x8 __attribute__((ext_vector_type(8)));
typedef float f32x4 __attribute__((ext_vector_type(4)));

__device__ __forceinline__ float siluf(float x){ return x / (1.f + __expf(-x)); }
__device__ __forceinline__ float geluf(float x){ return 0.5f*x*(1.f+erff(x*0.70710678118654752f)); }
__device__ __forceinline__ float softplusf(float x){ return fmaxf(x,0.f) + log1pf(__expf(-fabsf(x))); }

__device__ __forceinline__ void gl_lds16(const __bf16* g, const __bf16* lds_base){
  __builtin_amdgcn_global_load_lds(
      (const __attribute__((address_space(1))) unsigned int*)g,
      (__attribute__((address_space(3))) unsigned int*)lds_base, 16, 0, 0);
}

// ---------------- cast 4 weight matrices to bf16 ----------------
__global__ __launch_bounds__(256)
void cast_w_kernel(const float* __restrict__ inw, const float* __restrict__ outw,
                   const float* __restrict__ w1, const float* __restrict__ w2,
                   __bf16* __restrict__ dst){
  int i = blockIdx.x*256 + threadIdx.x;   // total 917504
  float v;
  if (i < 262144) v = inw[i];
  else if (i < 393216) v = outw[i-262144];
  else if (i < 655360) v = w1[i-393216];
  else v = w2[i-655360];
  dst[i] = (__bf16)v;
}

// ---------------- LayerNorm via LDS tile transpose; coalesced both sides ----------------
// block: (b, 32-l tile). 256 threads.
__global__ __launch_bounds__(256)
void ln_kernel(const float* __restrict__ x, const float* __restrict__ g,
               const float* __restrict__ bta, float* __restrict__ y,
               __bf16* __restrict__ ybf){
  __shared__ float tile[256*33];
  __shared__ float psum[8][32], psq[8][32];
  __shared__ float mus[32], rs[32];
  int bx = blockIdx.x;            // b*128 + t0
  int b = bx >> 7, t0 = bx & 127;
  int l0 = t0*32;
  int tid = threadIdx.x;
  int l = tid & 31, cr = tid >> 5;
  const float* xb = x + (((size_t)(b*256))<<12) + l0 + l;
  float sm = 0.f, sq = 0.f;
  #pragma unroll
  for (int k=0;k<32;k++){
    int c = cr + 8*k;
    float v = xb[(size_t)c<<12];
    tile[c*33 + l] = v;
    sm += v; sq += v*v;
  }
  psum[cr][l] = sm; psq[cr][l] = sq;
  __syncthreads();
  if (tid < 32){
    float s=0.f, s2=0.f;
    #pragma unroll
    for (int p=0;p<8;p++){ s += psum[p][tid]; s2 += psq[p][tid]; }
    float mu = s*(1.f/256.f);
    float var = s2*(1.f/256.f) - mu*mu;
    mus[tid] = mu; rs[tid] = rsqrtf(var + 1e-5f);
  }
  __syncthreads();
  int c = tid;
  float gc = g[c], bc = bta[c];
  float* yo = y + ((size_t)(b*L_SEQ + l0))*256 + c;
  __bf16* yb2 = ybf + ((size_t)(b*L_SEQ + l0))*256 + c;
  #pragma unroll
  for (int ll=0;ll<32;ll++){
    float v = tile[c*33 + ll];
    float o = (v - mus[ll])*rs[ll]*gc + bc;
    yo[(size_t)ll*256] = o;
    yb2[(size_t)ll*256] = (__bf16)o;
  }
}

// ---------------- bf16 MFMA GEMM ----------------
// BM: 128 (waves 2x2 of 64x64) or 64 (waves 1x4 of 64x32). BN fixed 128. BK=32.
template<int BM, int ACT, bool BIAS, bool RES, bool TOUT, bool OF32, bool OBF>
__global__ __launch_bounds__(256)
void mgemm_kernel(const __bf16* __restrict__ A, const __bf16* __restrict__ W,
                  const int K, const int N,
                  const float* __restrict__ bias, const float* __restrict__ res,
                  float* __restrict__ out32, __bf16* __restrict__ outbf){
  constexpr int NWN = (BM==128) ? 2 : 4;
  constexpr int NT  = 8 / NWN;
  __shared__ __bf16 Asm[BM*32];
  __shared__ __bf16 Bsm[128*32];
  __shared__ float tbuf[TOUT ? 4*32*65 : 1];
  const int tid = threadIdx.x;
  const int wid = tid >> 6, lane = tid & 63;
  const int lq = lane >> 4, lr = lane & 15;
  const int wmbase = (BM==128) ? (wid>>1)*64 : 0;
  const int wnbase = (BM==128) ? (wid&1)*64 : wid*32;
  const size_t m0 = (size_t)blockIdx.x * BM;
  const size_t n0 = (size_t)blockIdx.y * 128;

  const int rowS = tid >> 2;
  const int cg   = (tid & 3) ^ ((rowS >> 1) & 3);
  const __bf16* Ag = A + m0*K + (size_t)rowS*K + cg*8;
  const __bf16* Wg = W + n0*K + (size_t)rowS*K + cg*8;

  int a_off[4], b_off[NT];
  #pragma unroll
  for (int mt=0; mt<4; mt++){
    int r = wmbase + mt*16 + lr;
    a_off[mt] = r*64 + ((lq ^ ((r>>1)&3))<<4);
  }
  #pragma unroll
  for (int nt=0; nt<NT; nt++){
    int r = wnbase + nt*16 + lr;
    b_off[nt] = r*64 + ((lq ^ ((r>>1)&3))<<4);
  }

  f32x4 acc[4][NT] = {};

  for (int k0 = 0; k0 < K; k0 += 32){
    gl_lds16(Ag + k0, &Asm[wid*512]);
    if constexpr (BM==128) gl_lds16(Ag + (size_t)64*K + k0, &Asm[2048 + wid*512]);
    gl_lds16(Wg + k0, &Bsm[wid*512]);
    gl_lds16(Wg + (size_t)64*K + k0, &Bsm[2048 + wid*512]);
    __syncthreads();

    bf16x8 av[4], bv[NT];
    #pragma unroll
    for (int mt=0; mt<4; mt++) av[mt] = *(const bf16x8*)((const char*)Asm + a_off[mt]);
    #pragma unroll
    for (int nt=0; nt<NT; nt++) bv[nt] = *(const bf16x8*)((const char*)Bsm + b_off[nt]);
    #pragma unroll
    for (int mt=0; mt<4; mt++)
      #pragma unroll
      for (int nt=0; nt<NT; nt++)
        acc[mt][nt] = __builtin_amdgcn_mfma_f32_16x16x32_bf16(av[mt], bv[nt], acc[mt][nt], 0, 0, 0);
    __syncthreads();
  }

  // epilogue: C/D layout col=lane&15, row=(lane>>4)*4+reg
  if constexpr (TOUT){
    // stage per-wave tile to LDS, write coalesced rows of l (BM==64 assumed)
    float* tb = &tbuf[wid*(32*65)];
    #pragma unroll
    for (int mt=0; mt<4; mt++){
      #pragma unroll
      for (int r=0; r<4; r++){
        size_t m = m0 + wmbase + mt*16 + lq*4 + r;
        #pragma unroll
        for (int nt=0; nt<NT; nt++){
          size_t n = n0 + wnbase + nt*16 + lr;
          float v = acc[mt][nt][r];
          if (BIAS) v += bias[n];
          if (ACT==1) v = geluf(v);
          if (RES) v += res[m*(size_t)N + n];
          tb[(nt*16+lr)*65 + (mt*16 + lq*4 + r)] = v;
        }
      }
    }
    int bb = (int)(m0 >> 12);
    int l0 = (int)(m0 & 4095);
    int nb = (int)n0 + wnbase;
    #pragma unroll
    for (int n=0;n<32;n++){
      float v = tb[n*65 + lane];
      out32[((size_t)(bb*N + nb + n) << 12) + l0 + lane] = v;
    }
  } else {
    #pragma unroll
    for (int mt=0; mt<4; mt++){
      #pragma unroll
      for (int r=0; r<4; r++){
        size_t m = m0 + wmbase + mt*16 + lq*4 + r;
        #pragma unroll
        for (int nt=0; nt<NT; nt++){
          size_t n = n0 + wnbase + nt*16 + lr;
          float v = acc[mt][nt][r];
          if (BIAS) v += bias[n];
          if (ACT==1) v = geluf(v);
          if (RES) v += res[m*(size_t)N + n];
          if (OF32) out32[m*(size_t)N + n] = v;
          if (OBF)  outbf[m*(size_t)N + n] = (__bf16)v;
        }
      }
    }
  }
}

// ---------------- fp32 tiled GEMM (small shapes: x_proj N=48, dt_proj K=16) ----------------
template<int ACT, bool BIAS>
__global__ __launch_bounds__(256)
void gemm_kernel(const float* __restrict__ A, int lda,
                 const float* __restrict__ W, int ldw,
                 const float* __restrict__ bias,
                 float* __restrict__ out,
                 int M, int N, int K){
  __shared__ float As[16][68];
  __shared__ float Bs[16][68];
  int tid = threadIdx.x;
  int m0 = blockIdx.x*64, n0 = blockIdx.y*64;
  int row = tid >> 2, quad = tid & 3;
  int ty = tid >> 4, tx = tid & 15;
  float acc[4][4] = {};
  for (int k0 = 0; k0 < K; k0 += 16){
    float4 av = make_float4(0,0,0,0);
    if (m0+row < M)
      av = *(const float4*)(A + (size_t)(m0+row)*lda + k0 + quad*4);
    float4 bv = make_float4(0,0,0,0);
    if (n0+row < N)
      bv = *(const float4*)(W + (size_t)(n0+row)*ldw + k0 + quad*4);
    As[quad*4+0][row]=av.x; As[quad*4+1][row]=av.y; As[quad*4+2][row]=av.z; As[quad*4+3][row]=av.w;
    Bs[quad*4+0][row]=bv.x; Bs[quad*4+1][row]=bv.y; Bs[quad*4+2][row]=bv.z; Bs[quad*4+3][row]=bv.w;
    __syncthreads();
    #pragma unroll
    for (int kk=0; kk<16; kk++){
      float4 a = *(const float4*)&As[kk][ty*4];
      float4 b = *(const float4*)&Bs[kk][tx*4];
      acc[0][0] += a.x*b.x; acc[0][1] += a.x*b.y; acc[0][2] += a.x*b.z; acc[0][3] += a.x*b.w;
      acc[1][0] += a.y*b.x; acc[1][1] += a.y*b.y; acc[1][2] += a.y*b.z; acc[1][3] += a.y*b.w;
      acc[2][0] += a.z*b.x; acc[2][1] += a.z*b.y; acc[2][2] += a.z*b.z; acc[2][3] += a.z*b.w;
      acc[3][0] += a.w*b.x; acc[3][1] += a.w*b.y; acc[3][2] += a.w*b.z; acc[3][3] += a.w*b.w;
    }
    __syncthreads();
  }
  #pragma unroll
  for (int i=0;i<4;i++){
    int m = m0 + ty*4 + i;
    if (m >= M) continue;
    #pragma unroll
    for (int j=0;j<4;j++){
      int n = n0 + tx*4 + j;
      if (n >= N) continue;
      float v = acc[i][j];
      if (BIAS) v += bias[n];
      if (ACT==2) v = softplusf(v);
      out[(size_t)m*N + n] = v;
    }
  }
}

// ---------------- Depthwise causal conv (k=4) + SiLU (bf16 in, f32 out) ----------------
__global__ __launch_bounds__(256)
void conv_silu_kernel(const __bf16* __restrict__ xz, const float* __restrict__ w,
                      const float* __restrict__ cb, float* __restrict__ xc){
  int i = blockIdx.x*256 + threadIdx.x;   // NB*L*DIN = 4194304
  int d = i & 511;
  int l = (i >> 9) & 4095;
  int b = i >> 21;
  float acc = cb[d];
  float w0=w[d*4+0], w1=w[d*4+1], w2=w[d*4+2], w3=w[d*4+3];
  const __bf16* base = xz + (size_t)(b*L_SEQ)*1024 + d;
  if (l>=3) acc += w0*(float)base[(size_t)(l-3)*1024];
  if (l>=2) acc += w1*(float)base[(size_t)(l-2)*1024];
  if (l>=1) acc += w2*(float)base[(size_t)(l-1)*1024];
  acc += w3*(float)base[(size_t)l*1024];
  xc[i] = siluf(acc);
}

// ---------------- Scan phase A: thread-per-d, h[16] in registers ----------------
__global__ __launch_bounds__(256)
void scanA_kernel(const float* __restrict__ delta, const float* __restrict__ xc,
                  const float* __restrict__ xdbl, const float* __restrict__ A_log,
                  float* __restrict__ S, float* __restrict__ sumd){
  int bx = blockIdx.x;              // b(2) x c(128) x dg(2)
  int dg = bx & 1, c = (bx>>1) & 127, b = bx >> 8;
  int d = dg*256 + threadIdx.x;
  float a[16];
  #pragma unroll
  for (int s=0;s<16;s++) a[s] = -__expf(A_log[d*16+s]);
  float h[16] = {};
  float sd = 0.f;
  const size_t rb0 = (size_t)(b*L_SEQ + c*CHUNK);
  #pragma unroll 4
  for (int t=0;t<CHUNK;t++){
    size_t rb = rb0 + t;
    float dlt = delta[rb*512 + d];
    float xv  = xc[rb*512 + d];
    const float* __restrict__ Bp = xdbl + rb*48 + 16;   // block-uniform -> s_load
    sd += dlt;
    float dx = dlt*xv;
    #pragma unroll
    for (int s=0;s<16;s++)
      h[s] = __expf(dlt*a[s])*h[s] + dx*Bp[s];
  }
  size_t ci = (size_t)(b*NCHUNK + c)*512 + d;
  f32x4* Sv = (f32x4*)(S + ci*16);
  #pragma unroll
  for (int q=0;q<4;q++){
    f32x4 v; v[0]=h[q*4]; v[1]=h[q*4+1]; v[2]=h[q*4+2]; v[3]=h[q*4+3];
    Sv[q] = v;
  }
  sumd[ci] = sd;
}

// ---------------- Scan phase B: sequential combine (in place: S -> Hinit) ----------------
__global__ __launch_bounds__(256)
void scanB_kernel(float* __restrict__ SH, const float* __restrict__ sumd,
                  const float* __restrict__ A_log){
  int g = blockIdx.x*256 + threadIdx.x;  // 16384 = 2*512*16
  int s = g & 15, d = (g>>4) & 511, b = g >> 13;
  float Ads = -__expf(A_log[d*16+s]);
  float H = 0.f;
  for (int c=0;c<NCHUNK;c++){
    size_t ci = (size_t)(b*NCHUNK+c)*512 + d;
    float sv = SH[ci*16+s];
    SH[ci*16+s] = H;
    H = __expf(Ads*sumd[ci])*H + sv;
  }
}

// ---------------- Scan phase C: thread-per-d seeded re-scan ----------------
__global__ __launch_bounds__(256)
void scanC_kernel(const float* __restrict__ delta, const float* __restrict__ xc,
                  const float* __restrict__ xdbl, const __bf16* __restrict__ xz,
                  const float* __restrict__ A_log, const float* __restrict__ Dp,
                  const float* __restrict__ Hinit, __bf16* __restrict__ ys){
  int bx = blockIdx.x;
  int dg = bx & 1, c = (bx>>1) & 127, b = bx >> 8;
  int d = dg*256 + threadIdx.x;
  float a[16];
  #pragma unroll
  for (int s=0;s<16;s++) a[s] = -__expf(A_log[d*16+s]);
  size_t ci = (size_t)(b*NCHUNK + c)*512 + d;
  float h[16];
  const f32x4* Hv = (const f32x4*)(Hinit + ci*16);
  #pragma unroll
  for (int q=0;q<4;q++){
    f32x4 v = Hv[q];
    h[q*4]=v[0]; h[q*4+1]=v[1]; h[q*4+2]=v[2]; h[q*4+3]=v[3];
  }
  float Dv = Dp[d];
  const size_t rb0 = (size_t)(b*L_SEQ + c*CHUNK);
  #pragma unroll 4
  for (int t=0;t<CHUNK;t++){
    size_t rb = rb0 + t;
    float dlt = delta[rb*512 + d];
    float xv  = xc[rb*512 + d];
    const float* __restrict__ Bp = xdbl + rb*48 + 16;   // block-uniform -> s_load
    const float* __restrict__ Cp = xdbl + rb*48 + 32;
    float dx = dlt*xv;
    float y0=0.f,y1=0.f,y2=0.f,y3=0.f;
    #pragma unroll
    for (int q=0;q<4;q++){
      h[q*4+0] = __expf(dlt*a[q*4+0])*h[q*4+0] + dx*Bp[q*4+0];
      h[q*4+1] = __expf(dlt*a[q*4+1])*h[q*4+1] + dx*Bp[q*4+1];
      h[q*4+2] = __expf(dlt*a[q*4+2])*h[q*4+2] + dx*Bp[q*4+2];
      h[q*4+3] = __expf(dlt*a[q*4+3])*h[q*4+3] + dx*Bp[q*4+3];
    }
    #pragma unroll
    for (int q=0;q<4;q++){
      y0 += h[q*4+0]*Cp[q*4+0];
      y1 += h[q*4+1]*Cp[q*4+1];
      y2 += h[q*4+2]*Cp[q*4+2];
      y3 += h[q*4+3]*Cp[q*4+3];
    }
    float y = (y0+y1)+(y2+y3) + Dv*xv;
    float zv = (float)xz[rb*1024 + 512 + d];
    ys[rb*512 + d] = (__bf16)(y * siluf(zv));
  }
}

extern "C" void kernel_launch(void* const* d_in, const int* in_sizes, int n_in,
                              void* d_out, int out_size, void* d_ws, size_t ws_size,
                              hipStream_t stream){
  const float* x         = (const float*)d_in[0];
  const float* norm_g    = (const float*)d_in[1];
  const float* norm_b    = (const float*)d_in[2];
  const float* in_proj_w = (const float*)d_in[3];
  const float* conv_w    = (const float*)d_in[4];
  const float* conv_b    = (const float*)d_in[5];
  const float* x_proj_w  = (const float*)d_in[6];
  const float* dt_proj_w = (const float*)d_in[7];
  const float* dt_proj_b = (const float*)d_in[8];
  const float* A_log     = (const float*)d_in[9];
  const float* Dp        = (const float*)d_in[10];
  const float* out_proj_w= (const float*)d_in[11];
  const float* w1        = (const float*)d_in[12];
  const float* b1        = (const float*)d_in[13];
  const float* w2        = (const float*)d_in[14];
  const float* b2        = (const float*)d_in[15];

  float* ws    = (float*)d_ws;
  float* yln   = ws;                         // 2,097,152 f32
  __bf16* xzbf = (__bf16*)(yln + 2097152);   // 8,388,608 bf16 (4,194,304 slots)
  float* xc    = (float*)xzbf + 4194304;     // 4,194,304 f32
  float* delta = xc + 4194304;               // 4,194,304 f32
  float* xdbl  = delta + 4194304;            //   393,216 f32
  float* SH    = xdbl + 393216;              // 2,097,152 f32 (S, then Hinit in place)
  float* sumd  = SH + 2097152;               //   131,072 f32
  __bf16* wbf  = (__bf16*)(sumd + 131072);   //   917,504 bf16 (458,752 slots)
  float* dual  = (float*)wbf + 458752;       // 2,097,152 f32: ylnbf early, ysbf late
  __bf16* ylnbf = (__bf16*)dual;             // 2,097,152 bf16 (dead after in_proj)
  __bf16* ysbf  = (__bf16*)dual;             // 4,194,304 bf16 (written by scanC)
  float*  ymid   = delta;                    // after scanC, delta dead
  __bf16* ymidbf = (__bf16*)(delta + 2097152);
  __bf16* ffnh   = xzbf;                     // after scanC, xz dead
  __bf16* wbf_in = wbf;                      // 1024x256
  __bf16* wbf_out= wbf + 262144;             // 256x512
  __bf16* wbf_w1 = wbf + 393216;             // 1024x256
  __bf16* wbf_w2 = wbf + 655360;             // 256x1024

  // 0. weights -> bf16
  cast_w_kernel<<<3584, 256, 0, stream>>>(in_proj_w, out_proj_w, w1, w2, wbf);
  // 1. LayerNorm (tile-transposed, coalesced), f32 + bf16
  ln_kernel<<<NB*128, 256, 0, stream>>>(x, norm_g, norm_b, yln, ylnbf);
  // 2. in_proj (MFMA): (8192,256)x(1024,256)^T -> xz bf16
  mgemm_kernel<128,0,false,false,false,false,true><<<dim3(64,8), 256, 0, stream>>>(
      ylnbf, wbf_in, 256, 1024, nullptr, nullptr, nullptr, xzbf);
  // 3. depthwise causal conv + silu -> xc f32
  conv_silu_kernel<<<16384, 256, 0, stream>>>(xzbf, conv_w, conv_b, xc);
  // 4. x_proj (fp32): (8192,512)x(48,512)^T -> xdbl
  gemm_kernel<0,false><<<dim3(128,1), 256, 0, stream>>>(xc,512, x_proj_w,512, nullptr, xdbl, 8192,48,512);
  // 5. dt_proj + softplus (fp32): -> delta
  gemm_kernel<2,true><<<dim3(128,8), 256, 0, stream>>>(xdbl,48, dt_proj_w,16, dt_proj_b, delta, 8192,512,16);
  // 6-8. chunked selective scan (thread-per-d register formulation)
  scanA_kernel<<<NB*NCHUNK*2, 256, 0, stream>>>(delta, xc, xdbl, A_log, SH, sumd);
  scanB_kernel<<<64, 256, 0, stream>>>(SH, sumd, A_log);
  scanC_kernel<<<NB*NCHUNK*2, 256, 0, stream>>>(delta, xc, xdbl, xzbf, A_log, Dp, SH, ysbf);
  // 9. out_proj (MFMA) + residual(yln): -> ymid f32 + bf16
  mgemm_kernel<64,0,false,true,false,true,true><<<dim3(128,2), 256, 0, stream>>>(
      ysbf, wbf_out, 512, 256, nullptr, yln, ymid, ymidbf);
  // 10. ffn1 + gelu (MFMA): -> ffnh bf16
  mgemm_kernel<128,1,true,false,false,false,true><<<dim3(64,8), 256, 0, stream>>>(
      ymidbf, wbf_w1, 256, 1024, b1, nullptr, nullptr, ffnh);
  // 11. ffn2 + bias + residual(ymid) (MFMA), coalesced transposed write to (B,C,H,W)
  mgemm_kernel<64,0,true,true,true,true,false><<<dim3(128,2), 256, 0, stream>>>(
      ffnh, wbf_w2, 1024, 256, b2, ymid, (float*)d_out, nullptr);
}